// Round 1
// baseline (3453.685 us; speedup 1.0000x reference)
//
#include <hip/hip_runtime.h>
#include <cmath>

#define TT 1024
#define BB 256

__device__ __forceinline__ float lanebc(float v, int lane) {
    return __int_as_float(__builtin_amdgcn_readlane(__float_as_int(v), lane));
}

__device__ __forceinline__ float sigmoidf_(float x) {
    return 1.0f / (1.0f + __expf(-x));
}

// One block per batch element. Block size = 4H (thread j owns gate row j).
// Weights in registers; h broadcast across lanes via v_readlane; input
// projection fused (no xp buffer); x_{t+1} software-prefetched.
template<int H, int I>
__global__ __launch_bounds__(4*H) void lstm_layer(
    const float* __restrict__ x,     // [B, T, I]
    const float* __restrict__ Wih,   // [4H, I]
    const float* __restrict__ Whh,   // [4H, H]
    const float* __restrict__ bias,  // [4H]
    const float* __restrict__ h0,    // [B, H] or nullptr (-> zeros)
    const float* __restrict__ c0,    // [B, H] or nullptr
    float* __restrict__ out)         // [B, T, H]
{
    constexpr int FH   = 4 * H;
    constexpr int HREG = (H + 63) / 64;
    constexpr int XREG = (I + 63) / 64;
    const int b    = blockIdx.x;
    const int j    = threadIdx.x;   // 0..4H-1
    const int lane = j & 63;

    // --- weight rows into registers (once) ---
    float wih[I];
    float whh[H];
    #pragma unroll
    for (int k = 0; k < I; ++k) wih[k] = Wih[j * I + k];
    #pragma unroll
    for (int k = 0; k < H; ++k) whh[k] = Whh[j * H + k];
    const float bj = bias[j];

    __shared__ float g_lds[FH];
    __shared__ float h_lds[H];

    // --- state: h wave-distributed (lane l holds h[l+64q]), c in gate thread ---
    float hr[HREG];
    #pragma unroll
    for (int q = 0; q < HREG; ++q) {
        int hh = q * 64 + lane;
        hr[q] = (hh < H && h0 != nullptr) ? h0[b * H + hh] : 0.0f;
    }
    float c = 0.0f;
    if (j < H && c0 != nullptr) c = c0[b * H + j];

    const float* xb = x + (size_t)b * TT * I;
    float*       ob = out + (size_t)b * TT * H;

    // prefetch x_0 (wave-distributed like h)
    float xr[XREG];
    #pragma unroll
    for (int q = 0; q < XREG; ++q) {
        int kk = q * 64 + lane;
        xr[q] = (kk < I) ? xb[kk] : 0.0f;
    }

    for (int t = 0; t < TT; ++t) {
        // issue prefetch of x_{t+1}; latency hides under the GEMV below
        float xn[XREG];
        if (t + 1 < TT) {
            const float* xt = xb + (size_t)(t + 1) * I;
            #pragma unroll
            for (int q = 0; q < XREG; ++q) {
                int kk = q * 64 + lane;
                xn[q] = (kk < I) ? xt[kk] : 0.0f;
            }
        } else {
            #pragma unroll
            for (int q = 0; q < XREG; ++q) xn[q] = 0.0f;
        }

        // g[j] = b[j] + dot(x_t, Wih[j,:]) + dot(h_{t-1}, Whh[j,:])
        float acc[4] = {bj, 0.0f, 0.0f, 0.0f};
        #pragma unroll
        for (int k = 0; k < I; ++k) {
            float s = lanebc(xr[k >> 6], k & 63);
            acc[k & 3] += s * wih[k];
        }
        #pragma unroll
        for (int k = 0; k < H; ++k) {
            float s = lanebc(hr[k >> 6], k & 63);
            acc[k & 3] += s * whh[k];
        }
        float g = (acc[0] + acc[1]) + (acc[2] + acc[3]);

        g_lds[j] = g;
        __syncthreads();                      // bar A: all g ready

        if (j < H) {                          // gate/state update (PyTorch order i,f,g,o)
            float ig = sigmoidf_(g_lds[j]);
            float fg = sigmoidf_(g_lds[H + j]);
            float gg = tanhf(g_lds[2 * H + j]);
            float og = sigmoidf_(g_lds[3 * H + j]);
            c = fg * c + ig * gg;
            float h = og * tanhf(c);
            h_lds[j] = h;
            ob[(size_t)t * H + j] = h;
        }
        __syncthreads();                      // bar B: h ready

        // redistribute h_t into wave registers; swap in prefetched x
        #pragma unroll
        for (int q = 0; q < HREG; ++q) {
            int hh = q * 64 + lane;
            hr[q] = (hh < H) ? h_lds[hh] : 0.0f;
        }
        #pragma unroll
        for (int q = 0; q < XREG; ++q) xr[q] = xn[q];
    }
}

// out[bt] = tanh(dot(r[bt,:128], Wl) + bl)
__global__ __launch_bounds__(256) void final_proj(
    const float* __restrict__ r,   // [B*T, 128]
    const float* __restrict__ Wl,  // [128]
    const float* __restrict__ bl,  // [1]
    float* __restrict__ out)       // [B*T]
{
    __shared__ float wl[128];
    const int tid = threadIdx.x;
    if (tid < 128) wl[tid] = Wl[tid];
    __syncthreads();

    const int bt = blockIdx.x * 256 + tid;
    const float4* rr = reinterpret_cast<const float4*>(r + (size_t)bt * 128);
    float a0 = 0.f, a1 = 0.f, a2 = 0.f, a3 = 0.f;
    #pragma unroll
    for (int k = 0; k < 32; ++k) {
        float4 v = rr[k];
        a0 += v.x * wl[4 * k + 0];
        a1 += v.y * wl[4 * k + 1];
        a2 += v.z * wl[4 * k + 2];
        a3 += v.w * wl[4 * k + 3];
    }
    out[bt] = tanhf(((a0 + a1) + (a2 + a3)) + bl[0]);
}

extern "C" void kernel_launch(void* const* d_in, const int* in_sizes, int n_in,
                              void* d_out, int out_size, void* d_ws, size_t ws_size,
                              hipStream_t stream) {
    const float* input = (const float*)d_in[0];
    const float* h_0   = (const float*)d_in[1];   // [1,B,32]
    const float* c_0   = (const float*)d_in[2];
    const float* Wih0  = (const float*)d_in[3];
    const float* Whh0  = (const float*)d_in[4];
    const float* b0    = (const float*)d_in[5];
    const float* Wih1  = (const float*)d_in[6];
    const float* Whh1  = (const float*)d_in[7];
    const float* b1    = (const float*)d_in[8];
    const float* Wih2  = (const float*)d_in[9];
    const float* Whh2  = (const float*)d_in[10];
    const float* b2    = (const float*)d_in[11];
    const float* Wl    = (const float*)d_in[12];
    const float* bl    = (const float*)d_in[13];

    float* out = (float*)d_out;                       // [B*T] = 262144 floats
    float* r2  = out + (size_t)BB * TT;               // [B,T,128] (2nd output)
    float* r0  = (float*)d_ws;                        // [B,T,32]  (33.5 MB)
    float* r1  = r0 + (size_t)BB * TT * 32;           // [B,T,64]  (67 MB)

    hipLaunchKernelGGL((lstm_layer<32, 100>), dim3(BB), dim3(128), 0, stream,
                       input, Wih0, Whh0, b0, h_0, c_0, r0);
    hipLaunchKernelGGL((lstm_layer<64, 32>),  dim3(BB), dim3(256), 0, stream,
                       r0, Wih1, Whh1, b1, nullptr, nullptr, r1);
    hipLaunchKernelGGL((lstm_layer<128, 64>), dim3(BB), dim3(512), 0, stream,
                       r1, Wih2, Whh2, b2, nullptr, nullptr, r2);
    hipLaunchKernelGGL(final_proj, dim3(BB * TT / 256), dim3(256), 0, stream,
                       r2, Wl, bl, out);
}